// Round 4
// baseline (9408.458 us; speedup 1.0000x reference)
//
#include <hip/hip_runtime.h>
#include <math.h>

#define PITCH 72      // old layout (small kernels only)
#define NP 68         // new pitch: word(row r, col c) = 68r+c ; bank = (4r+c) mod 32
#define SW_BATCH 12
#define SW_SMALL 10
#define NPART 32
#define EPS2_ROT 1e-12f   // (1e-6)^2 : threshold compared on d^2

// Batch/eigensolve kernels: give the allocator a 256-VGPR budget (2 waves/EU
// target) so own[64]+pv[64] stay register-resident (R3 post-mortem: default
// occupancy targeting forced 92 VGPRs -> compiler 2-pass remat -> 2x DS ops).
#define KATTR __attribute__((amdgpu_flat_work_group_size(256, 256), amdgpu_waves_per_eu(1, 2)))

// ---- workspace float-offsets ----
#define OFF_ACCG 0
#define OFF_ACCT (NPART*4096)
#define OFF_BASE (2*NPART*4096)
#define SL_MNH  (OFF_BASE + 0*4096)
#define SL_MH   (OFF_BASE + 1*4096)
#define SL_WH   (OFF_BASE + 2*4096)
#define SL_P    (OFF_BASE + 3*4096)
#define SL_Q    (OFF_BASE + 4*4096)
#define SL_GH   (OFF_BASE + 5*4096)
#define SL_GNH  (OFF_BASE + 6*4096)
#define SL_MNH2 (OFF_BASE + 7*4096)
#define SL_WCH  (OFF_BASE + 8*4096)
#define OFF_VAR (OFF_BASE + 9*4096)
#define SL_SC   (OFF_BASE + 9*4096 + 1)

struct __align__(16) F4 { float v[4]; };

// ======================================================================
// OLD infrastructure (PITCH 72) — used only by the 1-block small kernels
// ======================================================================
struct __align__(16) Smem {
  float S0[64*PITCH];
  float S1[64*PITCH];
  float w2[64];
  float wc[64];
  float red[256];
};

__device__ __forceinline__ void g2s(float* dst, const float* __restrict__ src) {
  int t = threadIdx.x;
#pragma unroll
  for (int i = 0; i < 4; ++i) {
    int e4 = t + (i << 8);
    F4 vv = *(const F4*)&src[e4 * 4];
    *(F4*)&dst[(e4 >> 4) * PITCH + (e4 & 15) * 4] = vv;
  }
  __syncthreads();
}
__device__ __forceinline__ void s2g(float* __restrict__ dst, const float* src) {
  int t = threadIdx.x;
#pragma unroll
  for (int i = 0; i < 4; ++i) {
    int e4 = t + (i << 8);
    F4 vv = *(const F4*)&src[(e4 >> 4) * PITCH + (e4 & 15) * 4];
    *(F4*)&dst[e4 * 4] = vv;
  }
  __syncthreads();
}

template<int MODE>   // 0: S0<-S1*S0 ; 1: S0<-S0*S1
__device__ void mmX(Smem& sm) {
  int t = threadIdx.x;
  int R0 = t >> 4;
  int J = (t & 15) * 4;
  float acc[4][4] = {};
  for (int kb = 0; kb < 64; kb += 4) {
    F4 a4[4], b4[4];
#pragma unroll
    for (int i = 0; i < 4; ++i) {
      const float* L = (MODE == 0) ? sm.S1 : sm.S0;
      a4[i] = *(const F4*)&L[(R0 + 16 * i) * PITCH + kb];
    }
#pragma unroll
    for (int kk = 0; kk < 4; ++kk) {
      const float* Rp = (MODE == 0) ? sm.S0 : sm.S1;
      b4[kk] = *(const F4*)&Rp[(kb + kk) * PITCH + J];
    }
#pragma unroll
    for (int i = 0; i < 4; ++i)
#pragma unroll
      for (int kk = 0; kk < 4; ++kk)
#pragma unroll
        for (int m = 0; m < 4; ++m)
          acc[i][m] = fmaf(a4[i].v[kk], b4[kk].v[m], acc[i][m]);
  }
  __syncthreads();
#pragma unroll
  for (int i = 0; i < 4; ++i) {
    F4 o;
#pragma unroll
    for (int m = 0; m < 4; ++m) o.v[m] = acc[i][m];
    *(F4*)&sm.S0[(R0 + 16 * i) * PITCH + J] = o;
  }
  __syncthreads();
}

__device__ void reconT(Smem& sm) {
  __syncthreads();
  int t = threadIdx.x;
  int R0 = t >> 4;
  int J = (t & 15) * 4;
  float acc[4][4] = {};
  for (int k = 0; k < 64; ++k) {
    float w = sm.wc[k];
    float a[4];
#pragma unroll
    for (int i = 0; i < 4; ++i) a[i] = w * sm.S0[k * PITCH + R0 + 16 * i];
    F4 b = *(const F4*)&sm.S0[k * PITCH + J];
#pragma unroll
    for (int i = 0; i < 4; ++i)
#pragma unroll
      for (int m = 0; m < 4; ++m) acc[i][m] = fmaf(a[i], b.v[m], acc[i][m]);
  }
#pragma unroll
  for (int i = 0; i < 4; ++i) {
    F4 o;
#pragma unroll
    for (int m = 0; m < 4; ++m) o.v[m] = acc[i][m];
    *(F4*)&sm.S1[(R0 + 16 * i) * PITCH + J] = o;
  }
  __syncthreads();
}

__device__ float frob2(Smem& sm) {
  int t = threadIdx.x;
  float s = 0.f;
#pragma unroll
  for (int i = 0; i < 4; ++i) {
    int e4 = t + (i << 8);
    F4 vv = *(const F4*)&sm.S0[(e4 >> 4) * PITCH + (e4 & 15) * 4];
#pragma unroll
    for (int m = 0; m < 4; ++m) s = fmaf(vv.v[m], vv.v[m], s);
  }
  sm.red[t] = s;
  __syncthreads();
  for (int o = 128; o; o >>= 1) { if (t < o) sm.red[t] += sm.red[t + o]; __syncthreads(); }
  float f = sm.red[0];
  __syncthreads();
  return f;
}

// ---------- register-resident wave-synchronous one-sided Jacobi ----------
// lane l holds column l (= row l of the symmetric input) in own[64].
// XOR ordering: round m pairs lane l with lane l^m (m=1..63).
// Partner fetch via VOLATILE asm ds_bpermute: volatile asm cannot be
// rematerialized, so pv[64] must stay live -> SINGLE shuffle pass per round
// (the compiler's legal 2-pass remat of __shfl_xor doubled DS traffic, R3).
// Rule #18 guard: asm lgkmcnt(0) + sched_barrier(0) before any pv use.
__device__ __forceinline__ void hestenes_reg(float (&own)[64], float& w2out, int sweeps) {
  const int lane = threadIdx.x & 63;
  float nrm = 0.f;
#pragma unroll
  for (int i = 0; i < 64; ++i) nrm = fmaf(own[i], own[i], nrm);

  for (int s = 0; s < sweeps; ++s) {
    bool any = false;
    for (int m = 1; m < 64; ++m) {
      const int paddr = ((lane ^ m) << 2);
      float pv[64];
#pragma unroll
      for (int i = 0; i < 64; ++i)
        asm volatile("ds_bpermute_b32 %0, %1, %2"
                     : "=v"(pv[i]) : "v"(paddr), "v"(own[i]));
      asm volatile("s_waitcnt lgkmcnt(0)" ::: "memory");
      __builtin_amdgcn_sched_barrier(0);
      float d0 = 0.f, d1 = 0.f, d2 = 0.f, d3 = 0.f;
#pragma unroll
      for (int i = 0; i < 64; i += 4) {
        d0 = fmaf(own[i + 0], pv[i + 0], d0);
        d1 = fmaf(own[i + 1], pv[i + 1], d1);
        d2 = fmaf(own[i + 2], pv[i + 2], d2);
        d3 = fmaf(own[i + 3], pv[i + 3], d3);
      }
      float d = (d0 + d1) + (d2 + d3);
      float pn = __shfl_xor(nrm, m);
      if (d * d > EPS2_ROT * (nrm * pn)) {     // pair-uniform (bitwise-symmetric)
        any = true;
        bool lo = lane < (lane ^ m);           // exactly one lane of the pair
        float dpp = lo ? nrm : pn;
        float dqq = lo ? pn : nrm;
        float tau = (dqq - dpp) * (0.5f * __builtin_amdgcn_rcpf(d));
        float tt = __builtin_amdgcn_rcpf(fabsf(tau) +
                                         __builtin_amdgcn_sqrtf(fmaf(tau, tau, 1.f)));
        if (tau < 0.f) tt = -tt;
        float c = __builtin_amdgcn_rsqf(fmaf(tt, tt, 1.f));
        float s_ = tt * c;
        float sg = lo ? -s_ : s_;              // lo: c*p - s*q ; hi: c*q + s*p
#pragma unroll
        for (int i = 0; i < 64; ++i) own[i] = fmaf(sg, pv[i], c * own[i]);
        float td = tt * d;
        nrm += lo ? -td : td;                  // exact Jacobi diagonal update
      }
    }
    if (!__any((int)any)) break;
  }
  float w = 0.f;
#pragma unroll
  for (int i = 0; i < 64; ++i) w = fmaf(own[i], own[i], w);
  w2out = w;
}

// Small-kernel wrapper: wave 0 runs the register Jacobi on the PITCH-72 tile
// (replaces the barrier-per-round LDS hestenes: ~2x faster on 1-block kernels).
__device__ void hestenes_small(Smem& sm, int sweeps) {
  const int t = threadIdx.x;
  if (t < 64) {
    float own[64];
#pragma unroll
    for (int i = 0; i < 64; ++i) own[i] = sm.S0[t * PITCH + i];
    float w2;
    hestenes_reg(own, w2, sweeps);
#pragma unroll
    for (int i = 0; i < 64; ++i) sm.S0[t * PITCH + i] = own[i];
    sm.w2[t] = w2;
  }
  __syncthreads();
}

// ======================================================================
// NEW infrastructure (pitch 68) — batch kernels, 4 matrices per block
// ======================================================================
struct __align__(16) SmemK {      // k1,k2,k3 : 36.1 KB
  float A[64*NP];
  float Bop[64*NP];
  float wc[64];
  float red[256];
};
struct __align__(16) SmemK4 {     // k4 : 52.3 KB
  float A[64*NP];
  float P[64*NP];
  float Q[64*NP];
  float wc[64];
  float red[256];
};

__device__ __forceinline__ void g2s68(float* dst, const float* __restrict__ src) {
  int t = threadIdx.x;
#pragma unroll
  for (int i = 0; i < 4; ++i) {
    int e4 = t + (i << 8);
    F4 vv = *(const F4*)&src[e4 * 4];
    *(F4*)&dst[(e4 >> 4) * NP + (e4 & 15) * 4] = vv;
  }
  __syncthreads();
}
__device__ __forceinline__ void g2s68s(float* dst, const float* __restrict__ src, float sc) {
  int t = threadIdx.x;
#pragma unroll
  for (int i = 0; i < 4; ++i) {
    int e4 = t + (i << 8);
    F4 vv = *(const F4*)&src[e4 * 4];
#pragma unroll
    for (int m = 0; m < 4; ++m) vv.v[m] *= sc;
    *(F4*)&dst[(e4 >> 4) * NP + (e4 & 15) * 4] = vv;
  }
  __syncthreads();
}

// MODE 0: A <- Bo*A ; 1: A <- A*Bo ; 2: A <- A*Bo^T   (all in-place on A)
template<int MODE>
__device__ void mm68(float* A, const float* Bo) {
  int t = threadIdx.x;
  int R0 = t >> 4;
  if (MODE == 2) {
    int J0 = t & 15;
    float acc[4][4] = {};
    for (int kb = 0; kb < 64; kb += 4) {
      F4 a4[4];
#pragma unroll
      for (int i = 0; i < 4; ++i) a4[i] = *(const F4*)&A[(R0 + 16 * i) * NP + kb];
#pragma unroll
      for (int kk = 0; kk < 4; ++kk) {
        float b[4];
#pragma unroll
        for (int m = 0; m < 4; ++m) b[m] = Bo[(J0 + 16 * m) * NP + kb + kk];
#pragma unroll
        for (int i = 0; i < 4; ++i)
#pragma unroll
          for (int m = 0; m < 4; ++m) acc[i][m] = fmaf(a4[i].v[kk], b[m], acc[i][m]);
      }
    }
    __syncthreads();
#pragma unroll
    for (int i = 0; i < 4; ++i)
#pragma unroll
      for (int m = 0; m < 4; ++m)
        A[(R0 + 16 * i) * NP + J0 + 16 * m] = acc[i][m];
    __syncthreads();
  } else {
    int J = (t & 15) * 4;
    float acc[4][4] = {};
    for (int kb = 0; kb < 64; kb += 4) {
      F4 a4[4], b4[4];
#pragma unroll
      for (int i = 0; i < 4; ++i) {
        const float* L = (MODE == 0) ? Bo : A;
        a4[i] = *(const F4*)&L[(R0 + 16 * i) * NP + kb];
      }
#pragma unroll
      for (int kk = 0; kk < 4; ++kk) {
        const float* Rp = (MODE == 0) ? A : Bo;
        b4[kk] = *(const F4*)&Rp[(kb + kk) * NP + J];
      }
#pragma unroll
      for (int i = 0; i < 4; ++i)
#pragma unroll
        for (int kk = 0; kk < 4; ++kk)
#pragma unroll
          for (int m = 0; m < 4; ++m)
            acc[i][m] = fmaf(a4[i].v[kk], b4[kk].v[m], acc[i][m]);
    }
    __syncthreads();
#pragma unroll
    for (int i = 0; i < 4; ++i) {
      F4 o;
#pragma unroll
      for (int m = 0; m < 4; ++m) o.v[m] = acc[i][m];
      *(F4*)&A[(R0 + 16 * i) * NP + J] = o;
    }
    __syncthreads();
  }
}

__device__ float frob68(const float* A, float* red) {
  int t = threadIdx.x;
  float s = 0.f;
#pragma unroll
  for (int i = 0; i < 4; ++i) {
    int e4 = t + (i << 8);
    F4 vv = *(const F4*)&A[(e4 >> 4) * NP + (e4 & 15) * 4];
#pragma unroll
    for (int m = 0; m < 4; ++m) s = fmaf(vv.v[m], vv.v[m], s);
  }
  red[t] = s;
  __syncthreads();
  for (int o = 128; o; o >>= 1) { if (t < o) red[t] += red[t + o]; __syncthreads(); }
  float f = red[0];
  __syncthreads();
  return f;
}

// Z*Z -> global (row-major 64x64), reads Z (pitch 68), no LDS writes
__device__ void msq_store(const float* Z, float* __restrict__ gout) {
  int t = threadIdx.x;
  int R0 = t >> 4;
  int J = (t & 15) * 4;
  float acc[4][4] = {};
  for (int kb = 0; kb < 64; kb += 4) {
    F4 a4[4], b4[4];
#pragma unroll
    for (int i = 0; i < 4; ++i) a4[i] = *(const F4*)&Z[(R0 + 16 * i) * NP + kb];
#pragma unroll
    for (int kk = 0; kk < 4; ++kk) b4[kk] = *(const F4*)&Z[(kb + kk) * NP + J];
#pragma unroll
    for (int i = 0; i < 4; ++i)
#pragma unroll
      for (int kk = 0; kk < 4; ++kk)
#pragma unroll
        for (int m = 0; m < 4; ++m)
          acc[i][m] = fmaf(a4[i].v[kk], b4[kk].v[m], acc[i][m]);
  }
#pragma unroll
  for (int i = 0; i < 4; ++i) {
    F4 o;
#pragma unroll
    for (int m = 0; m < 4; ++m) o.v[m] = acc[i][m];
    *(F4*)&gout[(R0 + 16 * i) * 64 + J] = o;
  }
}

// ============================ kernels ============================

__global__ __launch_bounds__(256) void kzero(float* ws) {
  int i = blockIdx.x * 256 + threadIdx.x;
  if (i < OFF_BASE) ws[i] = 0.f;
  if (i == 0) ws[OFF_VAR] = 0.f;
}

// Mnh/Mh/Wh/Wc-eig -> P = Wc^{-1/2} Wh, Q = Mh Wc^{1/2}
__global__ KATTR void kprep(const float* __restrict__ weight,
                            const float* __restrict__ M,
                            float* ws) {
  __shared__ Smem sm;
  int t = threadIdx.x;
  g2s(sm.S0, M);
  hestenes_small(sm, SW_SMALL);
  if (t < 64) sm.wc[t] = powf(fmaxf(sm.w2[t], 1e-12f), -1.25f);
  reconT(sm); s2g(ws + SL_MNH, sm.S1);
  if (t < 64) sm.wc[t] = powf(fmaxf(sm.w2[t], 1e-12f), -0.75f);
  reconT(sm); s2g(ws + SL_MH, sm.S1);

  g2s(sm.S0, weight);
  hestenes_small(sm, SW_SMALL);
  if (t < 64) sm.wc[t] = powf(fmaxf(sm.w2[t], 1e-12f), -0.75f);
  reconT(sm); s2g(ws + SL_WH, sm.S1);

  g2s(sm.S0, ws + SL_MNH);
  mmX<1>(sm);
  g2s(sm.S1, ws + SL_MNH);
  mmX<1>(sm);
  hestenes_small(sm, SW_SMALL);
  if (t < 64) sm.wc[t] = powf(fmaxf(sm.w2[t], 1e-12f), -0.75f);
  reconT(sm); s2g(ws + SL_WCH, sm.S1);
  if (t < 64) sm.wc[t] = powf(fmaxf(sm.w2[t], 1e-12f), -1.25f);
  reconT(sm);
  g2s(sm.S0, ws + SL_WH);
  mmX<0>(sm);
  s2g(ws + SL_P, sm.S0);
  g2s(sm.S0, ws + SL_WCH);
  g2s(sm.S1, ws + SL_MH);
  mmX<0>(sm);
  s2g(ws + SL_Q, sm.S0);
}

// Xc_i = Mnh sqrt(X_i) Mnh -> out ; accumulate sum(Xc).  4 matrices/block.
__global__ KATTR void k1(const float* __restrict__ X,
                         float* __restrict__ out, float* ws) {
  __shared__ SmemK sm;
  int t = threadIdx.x;
  int w = t >> 6, lane = t & 63;
  size_t b = blockIdx.x;
  g2s68(sm.Bop, ws + SL_MNH);

  float own[64]; float w2;
  {
    const float* Xm = X + (b * 4 + w) * 4096 + (size_t)lane * 64;  // row lane = col lane (symmetric)
#pragma unroll
    for (int j = 0; j < 16; ++j) {
      F4 r = *(const F4*)&Xm[4 * j];
      own[4 * j + 0] = r.v[0]; own[4 * j + 1] = r.v[1];
      own[4 * j + 2] = r.v[2]; own[4 * j + 3] = r.v[3];
    }
  }
  hestenes_reg(own, w2, SW_BATCH);
  __syncthreads();

  int R0 = t >> 4, J = (t & 15) * 4;
  for (int m = 0; m < 4; ++m) {
    if (w == m) {
#pragma unroll
      for (int j = 0; j < 16; ++j) {
        F4 o = {{own[4 * j], own[4 * j + 1], own[4 * j + 2], own[4 * j + 3]}};
        *(F4*)&sm.A[lane * NP + 4 * j] = o;
      }
      sm.wc[lane] = powf(fmaxf(w2, 1e-12f), -0.75f);   // sqrt: lam^{1/2-2}
    }
    __syncthreads();
    mm68<1>(sm.A, sm.Bop);                              // rows = lam (Mnh u)^T
    // fused recon + epilogue (no LDS round-trip)
    float acc[4][4] = {};
    for (int k = 0; k < 64; ++k) {
      float wck = sm.wc[k];
      float a[4];
#pragma unroll
      for (int i = 0; i < 4; ++i) a[i] = wck * sm.A[k * NP + R0 + 16 * i];
      F4 bb = *(const F4*)&sm.A[k * NP + J];
#pragma unroll
      for (int i = 0; i < 4; ++i)
#pragma unroll
        for (int mc = 0; mc < 4; ++mc) acc[i][mc] = fmaf(a[i], bb.v[mc], acc[i][mc]);
    }
    float* Xc = out + (b * 4 + m) * 4096;
    float* accp = ws + OFF_ACCG + (size_t)((b * 4 + m) & (NPART - 1)) * 4096;
#pragma unroll
    for (int i = 0; i < 4; ++i) {
      F4 o;
#pragma unroll
      for (int mc = 0; mc < 4; ++mc) o.v[mc] = acc[i][mc];
      int base = (R0 + 16 * i) * 64 + J;
      *(F4*)&Xc[base] = o;
#pragma unroll
      for (int mc = 0; mc < 4; ++mc) atomicAdd(accp + base + mc, o.v[mc]);
    }
    __syncthreads();
  }
}

// G0 = mean(Xc); eig -> G0h, G0nh
__global__ KATTR void ksmall2(float* ws, float invB) {
  __shared__ Smem sm;
  int t = threadIdx.x;
#pragma unroll
  for (int i = 0; i < 4; ++i) {
    int e4 = t + (i << 8);
    F4 sum = {{0.f, 0.f, 0.f, 0.f}};
    for (int p = 0; p < NPART; ++p) {
      F4 vv = *(const F4*)&ws[OFF_ACCG + p * 4096 + e4 * 4];
#pragma unroll
      for (int m = 0; m < 4; ++m) sum.v[m] += vv.v[m];
    }
#pragma unroll
    for (int m = 0; m < 4; ++m) sum.v[m] *= invB;
    *(F4*)&sm.S0[(e4 >> 4) * PITCH + (e4 & 15) * 4] = sum;
  }
  __syncthreads();
  hestenes_small(sm, SW_SMALL);
  if (t < 64) sm.wc[t] = powf(fmaxf(sm.w2[t], 1e-12f), -0.75f);
  reconT(sm); s2g(ws + SL_GH, sm.S1);
  if (t < 64) sm.wc[t] = powf(fmaxf(sm.w2[t], 1e-12f), -1.25f);
  reconT(sm); s2g(ws + SL_GNH, sm.S1);
}

// accumulate sum_i log(G0nh Xc_i G0nh).  4 matrices/block.
__global__ KATTR void k2(const float* __restrict__ XcBuf, float* ws) {
  __shared__ SmemK sm;
  int t = threadIdx.x;
  int w = t >> 6, lane = t & 63;
  size_t b = blockIdx.x;
  g2s68(sm.Bop, ws + SL_GNH);

  float own[64]; float w2;
  for (int m = 0; m < 4; ++m) {
    g2s68(sm.A, XcBuf + (b * 4 + m) * 4096);
    mm68<1>(sm.A, sm.Bop);                    // Xc*Gnh
    mm68<0>(sm.A, sm.Bop);                    // Gnh*Xc*Gnh
    if (w == m) {
#pragma unroll
      for (int i = 0; i < 64; ++i) own[i] = sm.A[i * NP + lane];
    }
    __syncthreads();
  }
  hestenes_reg(own, w2, SW_BATCH);
  __syncthreads();

  int R0 = t >> 4, J = (t & 15) * 4;
  for (int m = 0; m < 4; ++m) {
    if (w == m) {
#pragma unroll
      for (int j = 0; j < 16; ++j) {
        F4 o = {{own[4 * j], own[4 * j + 1], own[4 * j + 2], own[4 * j + 3]}};
        *(F4*)&sm.A[lane * NP + 4 * j] = o;
      }
      float s2 = fmaxf(w2, 1e-12f);
      sm.wc[lane] = 0.5f * logf(s2) / s2;     // log(lam)/lam^2
    }
    __syncthreads();
    float acc[4][4] = {};
    for (int k = 0; k < 64; ++k) {
      float wck = sm.wc[k];
      float a[4];
#pragma unroll
      for (int i = 0; i < 4; ++i) a[i] = wck * sm.A[k * NP + R0 + 16 * i];
      F4 bb = *(const F4*)&sm.A[k * NP + J];
#pragma unroll
      for (int i = 0; i < 4; ++i)
#pragma unroll
        for (int mc = 0; mc < 4; ++mc) acc[i][mc] = fmaf(a[i], bb.v[mc], acc[i][mc]);
    }
    float* accp = ws + OFF_ACCT + (size_t)((b * 4 + m) & (NPART - 1)) * 4096;
#pragma unroll
    for (int i = 0; i < 4; ++i) {
      int base = (R0 + 16 * i) * 64 + J;
#pragma unroll
      for (int mc = 0; mc < 4; ++mc) atomicAdd(accp + base + mc, acc[i][mc]);
    }
    __syncthreads();
  }
}

// Tbar = mean ; mean_G = G0h exp(Tbar) G0h ; mnh = mean_G^{-1/2}
__global__ KATTR void ksmall3(float* ws, float invB) {
  __shared__ Smem sm;
  int t = threadIdx.x;
#pragma unroll
  for (int i = 0; i < 4; ++i) {
    int e4 = t + (i << 8);
    F4 sum = {{0.f, 0.f, 0.f, 0.f}};
    for (int p = 0; p < NPART; ++p) {
      F4 vv = *(const F4*)&ws[OFF_ACCT + p * 4096 + e4 * 4];
#pragma unroll
      for (int m = 0; m < 4; ++m) sum.v[m] += vv.v[m];
    }
#pragma unroll
    for (int m = 0; m < 4; ++m) sum.v[m] *= invB;
    *(F4*)&sm.S0[(e4 >> 4) * PITCH + (e4 & 15) * 4] = sum;
  }
  __syncthreads();
  float mu = sqrtf(frob2(sm)) + 1e-3f;
  if (t < 64) sm.S0[t * PITCH + t] += mu;
  __syncthreads();
  hestenes_small(sm, SW_SMALL);
  if (t < 64) {
    float s2 = fmaxf(sm.w2[t], 1e-12f);
    sm.wc[t] = expf(sqrtf(s2) - mu) / s2;
  }
  reconT(sm);
  g2s(sm.S0, ws + SL_GH);
  mmX<1>(sm);
  g2s(sm.S1, ws + SL_GH);
  mmX<1>(sm);
  hestenes_small(sm, SW_SMALL);
  if (t < 64) sm.wc[t] = powf(fmaxf(sm.w2[t], 1e-12f), -1.25f);
  reconT(sm); s2g(ws + SL_MNH2, sm.S1);
}

// T_i = log(mnh Xc_i mnh) (overwrites Xc) ; accumulate ||T||_F^2.  4/block.
__global__ KATTR void k3(float* __restrict__ buf, float* ws) {
  __shared__ SmemK sm;
  int t = threadIdx.x;
  int w = t >> 6, lane = t & 63;
  size_t b = blockIdx.x;
  g2s68(sm.Bop, ws + SL_MNH2);

  float own[64]; float w2;
  for (int m = 0; m < 4; ++m) {
    g2s68(sm.A, buf + (b * 4 + m) * 4096);
    mm68<1>(sm.A, sm.Bop);
    mm68<0>(sm.A, sm.Bop);
    if (w == m) {
#pragma unroll
      for (int i = 0; i < 64; ++i) own[i] = sm.A[i * NP + lane];
    }
    __syncthreads();
  }
  hestenes_reg(own, w2, SW_BATCH);
  __syncthreads();

  int R0 = t >> 4, J = (t & 15) * 4;
  for (int m = 0; m < 4; ++m) {
    if (w == m) {
#pragma unroll
      for (int j = 0; j < 16; ++j) {
        F4 o = {{own[4 * j], own[4 * j + 1], own[4 * j + 2], own[4 * j + 3]}};
        *(F4*)&sm.A[lane * NP + 4 * j] = o;
      }
      float s2 = fmaxf(w2, 1e-12f);
      sm.wc[lane] = 0.5f * logf(s2) / s2;
    }
    __syncthreads();
    float acc[4][4] = {};
    for (int k = 0; k < 64; ++k) {
      float wck = sm.wc[k];
      float a[4];
#pragma unroll
      for (int i = 0; i < 4; ++i) a[i] = wck * sm.A[k * NP + R0 + 16 * i];
      F4 bb = *(const F4*)&sm.A[k * NP + J];
#pragma unroll
      for (int i = 0; i < 4; ++i)
#pragma unroll
        for (int mc = 0; mc < 4; ++mc) acc[i][mc] = fmaf(a[i], bb.v[mc], acc[i][mc]);
    }
    float* Tg = buf + (b * 4 + m) * 4096;
    float ssq = 0.f;
#pragma unroll
    for (int i = 0; i < 4; ++i) {
      F4 o;
#pragma unroll
      for (int mc = 0; mc < 4; ++mc) o.v[mc] = acc[i][mc];
      int base = (R0 + 16 * i) * 64 + J;
      *(F4*)&Tg[base] = o;
#pragma unroll
      for (int mc = 0; mc < 4; ++mc) ssq = fmaf(o.v[mc], o.v[mc], ssq);
    }
    sm.red[t] = ssq;
    __syncthreads();
    for (int o = 128; o; o >>= 1) { if (t < o) sm.red[t] += sm.red[t + o]; __syncthreads(); }
    if (t == 0) atomicAdd(ws + OFF_VAR, sm.red[0]);
    __syncthreads();
  }
}

__global__ void kscale(float* ws, const float* __restrict__ shift, float invB) {
  if (threadIdx.x == 0 && blockIdx.x == 0) {
    float var = ws[OFF_VAR] * invB;
    ws[SL_SC] = shift[0] / sqrtf(var + 1e-5f);
  }
}

// Y_i = (Q exp(scale * P T_i P^T) Q^T)^2 -> buf.  4 matrices/block.
__global__ KATTR void k4(float* __restrict__ buf, float* ws) {
  __shared__ SmemK4 sm;
  int t = threadIdx.x;
  int w = t >> 6, lane = t & 63;
  size_t b = blockIdx.x;
  float sc = ws[SL_SC];
  g2s68(sm.P, ws + SL_P);
  g2s68(sm.Q, ws + SL_Q);

  float own[64]; float w2; float muw = 0.f;
  for (int m = 0; m < 4; ++m) {
    g2s68s(sm.A, buf + (b * 4 + m) * 4096, sc);   // scale*T
    mm68<0>(sm.A, sm.P);                          // P*(scT)
    mm68<2>(sm.A, sm.P);                          // P*(scT)*P^T (symmetric indefinite)
    float f = frob68(sm.A, sm.red);
    if (w == m) {
      muw = sqrtf(f) + 1e-3f;                     // SPD shift
#pragma unroll
      for (int i = 0; i < 64; ++i) {
        float v = sm.A[i * NP + lane];
        own[i] = v + ((i == lane) ? muw : 0.f);
      }
    }
    __syncthreads();
  }
  hestenes_reg(own, w2, SW_BATCH);
  __syncthreads();

  int R0 = t >> 4, J = (t & 15) * 4;
  for (int m = 0; m < 4; ++m) {
    if (w == m) {
#pragma unroll
      for (int j = 0; j < 16; ++j) {
        F4 o = {{own[4 * j], own[4 * j + 1], own[4 * j + 2], own[4 * j + 3]}};
        *(F4*)&sm.A[lane * NP + 4 * j] = o;
      }
      float s2 = fmaxf(w2, 1e-12f);
      sm.wc[lane] = expf(sqrtf(s2) - muw) / s2;
    }
    __syncthreads();
    mm68<2>(sm.A, sm.Q);                          // rows = lam (Q u)^T
    // recon -> sm.P (P is dead after pre-phase): Z = Q E Q^T
    float acc[4][4] = {};
    for (int k = 0; k < 64; ++k) {
      float wck = sm.wc[k];
      float a[4];
#pragma unroll
      for (int i = 0; i < 4; ++i) a[i] = wck * sm.A[k * NP + R0 + 16 * i];
      F4 bb = *(const F4*)&sm.A[k * NP + J];
#pragma unroll
      for (int i = 0; i < 4; ++i)
#pragma unroll
        for (int mc = 0; mc < 4; ++mc) acc[i][mc] = fmaf(a[i], bb.v[mc], acc[i][mc]);
    }
#pragma unroll
    for (int i = 0; i < 4; ++i) {
      F4 o;
#pragma unroll
      for (int mc = 0; mc < 4; ++mc) o.v[mc] = acc[i][mc];
      *(F4*)&sm.P[(R0 + 16 * i) * NP + J] = o;
    }
    __syncthreads();
    msq_store(sm.P, buf + (b * 4 + m) * 4096);    // Y = Z*Z -> global
    __syncthreads();
  }
}

extern "C" void kernel_launch(void* const* d_in, const int* in_sizes, int n_in,
                              void* d_out, int out_size, void* d_ws, size_t ws_size,
                              hipStream_t stream) {
  const float* X      = (const float*)d_in[0];
  const float* weight = (const float*)d_in[1];
  const float* M      = (const float*)d_in[2];
  const float* shift  = (const float*)d_in[3];
  float* out = (float*)d_out;
  float* ws  = (float*)d_ws;
  int B = in_sizes[0] / 4096;      // 4096 matrices of 64x64
  float invB = 1.f / (float)B;
  int G = B / 4;                   // 4 matrices per block

  hipLaunchKernelGGL(kzero,   dim3(OFF_BASE / 256), dim3(256), 0, stream, ws);
  hipLaunchKernelGGL(kprep,   dim3(1), dim3(256), 0, stream, weight, M, ws);
  hipLaunchKernelGGL(k1,      dim3(G), dim3(256), 0, stream, X, out, ws);
  hipLaunchKernelGGL(ksmall2, dim3(1), dim3(256), 0, stream, ws, invB);
  hipLaunchKernelGGL(k2,      dim3(G), dim3(256), 0, stream, out, ws);
  hipLaunchKernelGGL(ksmall3, dim3(1), dim3(256), 0, stream, ws, invB);
  hipLaunchKernelGGL(k3,      dim3(G), dim3(256), 0, stream, out, ws);
  hipLaunchKernelGGL(kscale,  dim3(1), dim3(64), 0, stream, ws, shift, invB);
  hipLaunchKernelGGL(k4,      dim3(G), dim3(256), 0, stream, out, ws);
}